// Round 5
// baseline (1048.787 us; speedup 1.0000x reference)
//
#include <hip/hip_runtime.h>
#include <hip/hip_bf16.h>

// R15: XCD-local channel slicing for all aggregation kernels. R14 showed MLP
// is not the limit: FETCH pinned at 264MB = hg(25.6MB) replicated ~8x across
// per-XCD L2s + csr/asrc. Fix: channel group g = blockIdx.x & 7 -> XCD g
// (round-robin dispatch heuristic); each XCD gathers only a 3.2MB channel
// slice (+0.4MB per-head asrcT) which stays L2-resident. GAT: 8ch group ==
// 1 head; asrc/adst stored transposed [head][node]. Edge loop is 8-lane
// serial, 4-way unrolled, zero reductions. csr streamed 8x (sequential).
// CSR build + matmuls unchanged (control). d_out FLOAT32, final no relu.

__device__ __forceinline__ float leaky02(float x) { return x > 0.0f ? x : 0.2f * x; }

#define NB_PART 64   // partition blocks (hist/scatter chunks)

// ---------- phase 1a: per-chunk bucket histogram ----------
__global__ __launch_bounds__(1024) void hist_kernel(
    const int* __restrict__ dst, int* __restrict__ hist, int ne, int nbkt) {
  __shared__ int h[512];
  const int tid = threadIdx.x;
  for (int i = tid; i < 512; i += 1024) h[i] = 0;
  __syncthreads();
  const int chunk = (ne + NB_PART - 1) / NB_PART;
  const int beg = blockIdx.x * chunk;
  const int end = min(beg + chunk, ne);
  for (int e = beg + tid; e < end; e += 1024) atomicAdd(&h[dst[e] >> 8], 1);
  __syncthreads();
  for (int i = tid; i < nbkt; i += 1024) hist[blockIdx.x * nbkt + i] = h[i];
}

// ---------- phase 1b: per-bucket cross-chunk prefix + bucket bases ----------
__global__ __launch_bounds__(512) void pscan_kernel(
    int* __restrict__ hist, int* __restrict__ bktBase, int nbkt, int ne) {
  __shared__ int tot[512];
  const int t = threadIdx.x;
  int run = 0;
  if (t < nbkt) {
    for (int b = 0; b < NB_PART; ++b) {
      int v = hist[b * nbkt + t];
      hist[b * nbkt + t] = run;  // per-chunk exclusive prefix within bucket
      run += v;
    }
  }
  tot[t] = (t < nbkt) ? run : 0;
  __syncthreads();
  for (int off = 1; off < 512; off <<= 1) {
    int u = (t >= off) ? tot[t - off] : 0;
    __syncthreads();
    tot[t] += u;
    __syncthreads();
  }
  if (t < nbkt) bktBase[t] = tot[t] - run;  // exclusive over buckets
  if (t == 0) bktBase[nbkt] = ne;
}

// ---------- phase 1c: partition (src,dst) into bucket-contiguous records ----------
__global__ __launch_bounds__(1024) void part_kernel(
    const int* __restrict__ src, const int* __restrict__ dst,
    const int* __restrict__ hist, const int* __restrict__ bktBase,
    int2* __restrict__ part, int ne, int nbkt) {
  __shared__ int cur[512];
  const int tid = threadIdx.x;
  for (int i = tid; i < nbkt; i += 1024)
    cur[i] = bktBase[i] + hist[blockIdx.x * nbkt + i];
  __syncthreads();
  const int chunk = (ne + NB_PART - 1) / NB_PART;
  const int beg = blockIdx.x * chunk;
  const int end = min(beg + chunk, ne);
  for (int e = beg + tid; e < end; e += 1024) {
    int d = dst[e];
    int s = src[e];
    int pos = atomicAdd(&cur[d >> 8], 1);
    part[pos] = make_int2(s, d);
  }
}

// ---------- phase 2: per-bucket rowptr + dinv + csr scatter (all LDS-local) ----------
__global__ __launch_bounds__(256) void build_kernel(
    const int2* __restrict__ part, const int* __restrict__ bktBase,
    int* __restrict__ rowptr, int* __restrict__ csr, float* __restrict__ dinv,
    int n, int ne) {
  __shared__ int cnt[256], sc[256], cur[256];
  const int b = blockIdx.x, tid = threadIdx.x;
  const int lo = b << 8;
  const int ebeg = bktBase[b], eend = bktBase[b + 1];
  cnt[tid] = 0;
  __syncthreads();
  for (int e = ebeg + tid; e < eend; e += 256) atomicAdd(&cnt[part[e].y - lo], 1);
  __syncthreads();
  sc[tid] = cnt[tid];
  __syncthreads();
  for (int off = 1; off < 256; off <<= 1) {
    int u = (tid >= off) ? sc[tid - off] : 0;
    __syncthreads();
    sc[tid] += u;
    __syncthreads();
  }
  const int excl = sc[tid] - cnt[tid];
  const int node = lo + tid;
  if (node < n) {
    rowptr[node] = ebeg + excl;
    dinv[node] = rsqrtf((float)(cnt[tid] + 1));  // +1 self-loop
  }
  cur[tid] = ebeg + excl;
  __syncthreads();
  for (int e = ebeg + tid; e < eend; e += 256) {
    int2 p = part[e];
    int pos = atomicAdd(&cur[p.y - lo], 1);  // LDS atomic
    csr[pos] = p.x;                          // write within ~16KB L2-hot window
  }
  if (b == 0 && tid == 0) rowptr[n] = ne;
}

// ---------- dense matmul: C[n,64] = A[n,K] @ W[K,64], register-tiled ----------
template<int K, bool SCALE>
__global__ __launch_bounds__(256) void matmul_kernel(
    const float* __restrict__ A, const float* __restrict__ W,
    const float* __restrict__ dinv, float* __restrict__ C, int n) {
  __shared__ float sW[K * 64];
  __shared__ float sA[64 * (K + 1)];
  const int tid = threadIdx.x;
  const int row0 = blockIdx.x * 64;
  for (int i = tid; i < K * 16; i += 256)
    reinterpret_cast<float4*>(sW)[i] = reinterpret_cast<const float4*>(W)[i];
  const int f4r = K / 4;
  for (int i = tid; i < 64 * f4r; i += 256) {
    int r = i / f4r, f = i - r * f4r;
    int row = row0 + r;
    float4 v = (row < n)
        ? reinterpret_cast<const float4*>(&A[(long)row * K])[f]
        : make_float4(0.f, 0.f, 0.f, 0.f);
    float* p = &sA[r * (K + 1) + f * 4];
    p[0] = v.x; p[1] = v.y; p[2] = v.z; p[3] = v.w;
  }
  __syncthreads();
  const int tc = tid & 15, tr = tid >> 4;
  const int c0 = tc * 4, r0 = tr * 4;
  float4 acc0 = {0,0,0,0}, acc1 = {0,0,0,0}, acc2 = {0,0,0,0}, acc3 = {0,0,0,0};
  const float* a0 = &sA[(r0 + 0) * (K + 1)];
  const float* a1 = &sA[(r0 + 1) * (K + 1)];
  const float* a2 = &sA[(r0 + 2) * (K + 1)];
  const float* a3 = &sA[(r0 + 3) * (K + 1)];
#pragma unroll 8
  for (int k = 0; k < K; ++k) {
    float4 w = *reinterpret_cast<const float4*>(&sW[k * 64 + c0]);
    float x0 = a0[k], x1 = a1[k], x2 = a2[k], x3 = a3[k];
    acc0.x = fmaf(x0, w.x, acc0.x); acc0.y = fmaf(x0, w.y, acc0.y);
    acc0.z = fmaf(x0, w.z, acc0.z); acc0.w = fmaf(x0, w.w, acc0.w);
    acc1.x = fmaf(x1, w.x, acc1.x); acc1.y = fmaf(x1, w.y, acc1.y);
    acc1.z = fmaf(x1, w.z, acc1.z); acc1.w = fmaf(x1, w.w, acc1.w);
    acc2.x = fmaf(x2, w.x, acc2.x); acc2.y = fmaf(x2, w.y, acc2.y);
    acc2.z = fmaf(x2, w.z, acc2.z); acc2.w = fmaf(x2, w.w, acc2.w);
    acc3.x = fmaf(x3, w.x, acc3.x); acc3.y = fmaf(x3, w.y, acc3.y);
    acc3.z = fmaf(x3, w.z, acc3.z); acc3.w = fmaf(x3, w.w, acc3.w);
  }
  float4 accs[4] = {acc0, acc1, acc2, acc3};
#pragma unroll
  for (int i = 0; i < 4; ++i) {
    int row = row0 + r0 + i;
    if (row < n) {
      float s = SCALE ? dinv[row] : 1.0f;
      float4 o = make_float4(accs[i].x * s, accs[i].y * s,
                             accs[i].z * s, accs[i].w * s);
      *reinterpret_cast<float4*>(&C[(long)row * 64 + c0]) = o;
    }
  }
}

// ---------- channel-sliced GCN aggregate ----------
// grid = 8 * ceil(n/32); channel group g = blockIdx&7 -> XCD g (round-robin).
// 8 lanes per node, lane = one channel of group; serial edge loop, 4-way unroll.
template<bool RELU>
__global__ __launch_bounds__(256) void gcn_layer_kernel(
    const int* __restrict__ rowptr, const int* __restrict__ csr,
    const float* __restrict__ hs, const float* __restrict__ dinv,
    const float* __restrict__ bias, float* __restrict__ out, int n) {
  const int g = blockIdx.x & 7;
  const int node = (blockIdx.x >> 3) * 32 + (threadIdx.x >> 3);
  if (node >= n) return;
  const int c = g * 8 + (threadIdx.x & 7);
  const int beg = rowptr[node], end = rowptr[node + 1];
  float a0 = 0.f, a1 = 0.f, a2 = 0.f, a3 = 0.f;
  int j = beg;
  for (; j + 4 <= end; j += 4) {
    int s0 = csr[j], s1 = csr[j + 1], s2 = csr[j + 2], s3 = csr[j + 3];
    a0 += hs[(long)s0 * 64 + c];
    a1 += hs[(long)s1 * 64 + c];
    a2 += hs[(long)s2 * 64 + c];
    a3 += hs[(long)s3 * 64 + c];
  }
  for (; j < end; ++j) a0 += hs[(long)csr[j] * 64 + c];
  a0 += hs[(long)node * 64 + c];  // self-loop (hs pre-scaled by dinv)
  float acc = (a0 + a1) + (a2 + a3);
  float v = fmaf(dinv[node], acc, bias[c]);
  if (RELU) v = fmaxf(v, 0.f);
  out[(long)node * 64 + c] = v;
}

// ---------- GAT per-node attention logits (TRANSPOSED [head][node] out) ----------
__global__ void gat_alpha_kernel(
    const float* __restrict__ hg, const float* __restrict__ att_src, const float* __restrict__ att_dst,
    float* __restrict__ asT, float* __restrict__ adT, int n) {
  int i = blockIdx.x * 256 + threadIdx.x;
  if (i >= n * 8) return;
  int nrow = i >> 3, h = i & 7;
  const float* hp = &hg[(long)nrow * 64 + h * 8];
  float ss = 0.f, dd = 0.f;
#pragma unroll
  for (int c = 0; c < 8; ++c) {
    float v = hp[c];
    ss = fmaf(v, att_src[h * 8 + c], ss);
    dd = fmaf(v, att_dst[h * 8 + c], dd);
  }
  asT[(long)h * n + nrow] = ss;
  adT[(long)h * n + nrow] = dd;
}

// ---------- channel-sliced GAT: head h = blockIdx&7 == channel group ----------
__global__ __launch_bounds__(256) void gat_layer_kernel(
    const int* __restrict__ rowptr, const int* __restrict__ csr,
    const float* __restrict__ hg, const float* __restrict__ asT,
    const float* __restrict__ adT, const float* __restrict__ bg,
    float* __restrict__ out, int n) {
  const int h = blockIdx.x & 7;
  const int node = (blockIdx.x >> 3) * 32 + (threadIdx.x >> 3);
  if (node >= n) return;
  const int c = h * 8 + (threadIdx.x & 7);
  const float* __restrict__ as_h = asT + (long)h * n;
  const float adn = adT[(long)h * n + node];
  const int beg = rowptr[node], end = rowptr[node + 1];
  float z0 = 0.f, z1 = 0.f, z2 = 0.f, z3 = 0.f;
  float a0 = 0.f, a1 = 0.f, a2 = 0.f, a3 = 0.f;
  int j = beg;
  for (; j + 4 <= end; j += 4) {
    int s0 = csr[j], s1 = csr[j + 1], s2 = csr[j + 2], s3 = csr[j + 3];
    float p0 = __expf(leaky02(as_h[s0] + adn));
    float p1 = __expf(leaky02(as_h[s1] + adn));
    float p2 = __expf(leaky02(as_h[s2] + adn));
    float p3 = __expf(leaky02(as_h[s3] + adn));
    a0 = fmaf(p0, hg[(long)s0 * 64 + c], a0); z0 += p0;
    a1 = fmaf(p1, hg[(long)s1 * 64 + c], a1); z1 += p1;
    a2 = fmaf(p2, hg[(long)s2 * 64 + c], a2); z2 += p2;
    a3 = fmaf(p3, hg[(long)s3 * 64 + c], a3); z3 += p3;
  }
  for (; j < end; ++j) {
    int s = csr[j];
    float p = __expf(leaky02(as_h[s] + adn));
    a0 = fmaf(p, hg[(long)s * 64 + c], a0); z0 += p;
  }
  {  // self-loop
    float p = __expf(leaky02(as_h[node] + adn));
    a0 = fmaf(p, hg[(long)node * 64 + c], a0); z0 += p;
  }
  float z = (z0 + z1) + (z2 + z3);
  float acc = (a0 + a1) + (a2 + a3);
  float v = fmaxf(fmaf(acc, 1.0f / z, bg[c]), 0.f);
  out[(long)node * 64 + c] = v;
}

extern "C" void kernel_launch(void* const* d_in, const int* in_sizes, int n_in,
                              void* d_out, int out_size, void* d_ws, size_t ws_size,
                              hipStream_t stream) {
  const float* x  = (const float*)d_in[0];
  const int* ei   = (const int*)d_in[1];
  const float* W0 = (const float*)d_in[2];
  const float* b0 = (const float*)d_in[3];
  const float* Wg = (const float*)d_in[4];
  const float* av = (const float*)d_in[5];
  const float* aw = (const float*)d_in[6];
  const float* bg = (const float*)d_in[7];
  const float* W2 = (const float*)d_in[8];
  const float* b2 = (const float*)d_in[9];
  const float* W3 = (const float*)d_in[10];
  const float* b3 = (const float*)d_in[11];

  const int N = in_sizes[0] / 128;
  const int E = in_sizes[1] / 2;
  const int* src = ei;
  const int* dst = ei + E;
  const int nbkt = (N + 255) >> 8;  // 391 for N=100000 (<=512 supported)

  char* base = (char*)d_ws;
  size_t off = 0;
  auto alloc = [&](size_t bytes) {
    void* p = base + off;
    off = (off + bytes + 255) & ~(size_t)255;
    return p;
  };
  int*   hist    = (int*)alloc((size_t)NB_PART * nbkt * 4);
  int*   bktBase = (int*)alloc((size_t)(nbkt + 1) * 4);
  int*   rowptr  = (int*)alloc((size_t)(N + 1) * 4);
  int*   csr     = (int*)alloc((size_t)E * 4);
  float* dinv    = (float*)alloc((size_t)N * 4);
  float* as_     = (float*)alloc((size_t)N * 8 * 4);
  float* ad_     = (float*)alloc((size_t)N * 8 * 4);
  float* bufA    = (float*)alloc((size_t)N * 64 * 4);
  float* bufB    = (float*)alloc((size_t)N * 64 * 4);
  int2*  part    = (int2*)bufA;  // 12.8MB alias; dead before first matmul writes bufA
  (void)ws_size; (void)n_in; (void)out_size;

  const int gN8   = (N * 8 + 255) / 256;
  const int gMM   = (N + 63) / 64;
  const int gAgg  = 8 * ((N + 31) / 32);  // channel-sliced aggregation grid

  // ---- CSR build: bucketed partition, L2-local scatter ----
  hist_kernel<<<NB_PART, 1024, 0, stream>>>(dst, hist, E, nbkt);
  pscan_kernel<<<1, 512, 0, stream>>>(hist, bktBase, nbkt, E);
  part_kernel<<<NB_PART, 1024, 0, stream>>>(src, dst, hist, bktBase, part, E, nbkt);
  build_kernel<<<nbkt, 256, 0, stream>>>(part, bktBase, rowptr, csr, dinv, N, E);

  // ---- GCN0 ----
  matmul_kernel<128, true><<<gMM, 256, 0, stream>>>(x, W0, dinv, bufA, N);
  gcn_layer_kernel<true><<<gAgg, 256, 0, stream>>>(rowptr, csr, bufA, dinv, b0, bufB, N);

  // ---- GAT ----
  matmul_kernel<64, false><<<gMM, 256, 0, stream>>>(bufB, Wg, nullptr, bufA, N);
  gat_alpha_kernel<<<gN8, 256, 0, stream>>>(bufA, av, aw, as_, ad_, N);
  gat_layer_kernel<<<gAgg, 256, 0, stream>>>(rowptr, csr, bufA, as_, ad_, bg, bufB, N);

  // ---- GCN2 ----
  matmul_kernel<64, true><<<gMM, 256, 0, stream>>>(bufB, W2, dinv, bufA, N);
  gcn_layer_kernel<true><<<gAgg, 256, 0, stream>>>(rowptr, csr, bufA, dinv, b2, bufB, N);

  // ---- GCN3: final layer, no relu, FLOAT32 out ----
  matmul_kernel<64, true><<<gMM, 256, 0, stream>>>(bufB, W3, dinv, bufA, N);
  gcn_layer_kernel<false><<<gAgg, 256, 0, stream>>>(rowptr, csr, bufA, dinv, b3,
                                                    (float*)d_out, N);
}

// Round 6
// 699.328 us; speedup vs baseline: 1.4997x; 1.4997x over previous
//
#include <hip/hip_runtime.h>
#include <hip/hip_bf16.h>

// R16: fix R15's channel slicing with a slice-major feature layout [8][N][8].
// R15 failed because slices were strided (32B used per 64B line, 8x groups ->
// 512B/edge, FETCH 683MB). Now matmul writes features sliced-contiguous; each
// XCD's group slice = 3.2MB contiguous + 0.4MB asT -> L2-resident. Agg reads
// 32B coalesced per edge; csr streamed 8x (sequential, cheap). Agg output
// standard [node][64] for the next matmul. blockIdx&7 -> XCD (round-robin
// dispatch, learn_hip m157). CSR build unchanged. d_out FLOAT32, final no relu.

__device__ __forceinline__ float leaky02(float x) { return x > 0.0f ? x : 0.2f * x; }

#define NB_PART 64   // partition blocks (hist/scatter chunks)

// ---------- phase 1a: per-chunk bucket histogram ----------
__global__ __launch_bounds__(1024) void hist_kernel(
    const int* __restrict__ dst, int* __restrict__ hist, int ne, int nbkt) {
  __shared__ int h[512];
  const int tid = threadIdx.x;
  for (int i = tid; i < 512; i += 1024) h[i] = 0;
  __syncthreads();
  const int chunk = (ne + NB_PART - 1) / NB_PART;
  const int beg = blockIdx.x * chunk;
  const int end = min(beg + chunk, ne);
  for (int e = beg + tid; e < end; e += 1024) atomicAdd(&h[dst[e] >> 8], 1);
  __syncthreads();
  for (int i = tid; i < nbkt; i += 1024) hist[blockIdx.x * nbkt + i] = h[i];
}

// ---------- phase 1b: per-bucket cross-chunk prefix + bucket bases ----------
__global__ __launch_bounds__(512) void pscan_kernel(
    int* __restrict__ hist, int* __restrict__ bktBase, int nbkt, int ne) {
  __shared__ int tot[512];
  const int t = threadIdx.x;
  int run = 0;
  if (t < nbkt) {
    for (int b = 0; b < NB_PART; ++b) {
      int v = hist[b * nbkt + t];
      hist[b * nbkt + t] = run;  // per-chunk exclusive prefix within bucket
      run += v;
    }
  }
  tot[t] = (t < nbkt) ? run : 0;
  __syncthreads();
  for (int off = 1; off < 512; off <<= 1) {
    int u = (t >= off) ? tot[t - off] : 0;
    __syncthreads();
    tot[t] += u;
    __syncthreads();
  }
  if (t < nbkt) bktBase[t] = tot[t] - run;  // exclusive over buckets
  if (t == 0) bktBase[nbkt] = ne;
}

// ---------- phase 1c: partition (src,dst) into bucket-contiguous records ----------
__global__ __launch_bounds__(1024) void part_kernel(
    const int* __restrict__ src, const int* __restrict__ dst,
    const int* __restrict__ hist, const int* __restrict__ bktBase,
    int2* __restrict__ part, int ne, int nbkt) {
  __shared__ int cur[512];
  const int tid = threadIdx.x;
  for (int i = tid; i < nbkt; i += 1024)
    cur[i] = bktBase[i] + hist[blockIdx.x * nbkt + i];
  __syncthreads();
  const int chunk = (ne + NB_PART - 1) / NB_PART;
  const int beg = blockIdx.x * chunk;
  const int end = min(beg + chunk, ne);
  for (int e = beg + tid; e < end; e += 1024) {
    int d = dst[e];
    int s = src[e];
    int pos = atomicAdd(&cur[d >> 8], 1);
    part[pos] = make_int2(s, d);
  }
}

// ---------- phase 2: per-bucket rowptr + dinv + csr scatter (all LDS-local) ----------
__global__ __launch_bounds__(256) void build_kernel(
    const int2* __restrict__ part, const int* __restrict__ bktBase,
    int* __restrict__ rowptr, int* __restrict__ csr, float* __restrict__ dinv,
    int n, int ne) {
  __shared__ int cnt[256], sc[256], cur[256];
  const int b = blockIdx.x, tid = threadIdx.x;
  const int lo = b << 8;
  const int ebeg = bktBase[b], eend = bktBase[b + 1];
  cnt[tid] = 0;
  __syncthreads();
  for (int e = ebeg + tid; e < eend; e += 256) atomicAdd(&cnt[part[e].y - lo], 1);
  __syncthreads();
  sc[tid] = cnt[tid];
  __syncthreads();
  for (int off = 1; off < 256; off <<= 1) {
    int u = (tid >= off) ? sc[tid - off] : 0;
    __syncthreads();
    sc[tid] += u;
    __syncthreads();
  }
  const int excl = sc[tid] - cnt[tid];
  const int node = lo + tid;
  if (node < n) {
    rowptr[node] = ebeg + excl;
    dinv[node] = rsqrtf((float)(cnt[tid] + 1));  // +1 self-loop
  }
  cur[tid] = ebeg + excl;
  __syncthreads();
  for (int e = ebeg + tid; e < eend; e += 256) {
    int2 p = part[e];
    int pos = atomicAdd(&cur[p.y - lo], 1);  // LDS atomic
    csr[pos] = p.x;                          // write within ~16KB L2-hot window
  }
  if (b == 0 && tid == 0) rowptr[n] = ne;
}

// ---------- dense matmul: C = A[n,K] @ W[K,64], SLICED output [8][n][8] ----------
// C[((c>>3)*n + row)*8 + (c&7)]; optional per-row dinv scale.
template<int K, bool SCALE>
__global__ __launch_bounds__(256) void matmul_kernel(
    const float* __restrict__ A, const float* __restrict__ W,
    const float* __restrict__ dinv, float* __restrict__ C, int n) {
  __shared__ float sW[K * 64];
  __shared__ float sA[64 * (K + 1)];
  const int tid = threadIdx.x;
  const int row0 = blockIdx.x * 64;
  for (int i = tid; i < K * 16; i += 256)
    reinterpret_cast<float4*>(sW)[i] = reinterpret_cast<const float4*>(W)[i];
  const int f4r = K / 4;
  for (int i = tid; i < 64 * f4r; i += 256) {
    int r = i / f4r, f = i - r * f4r;
    int row = row0 + r;
    float4 v = (row < n)
        ? reinterpret_cast<const float4*>(&A[(long)row * K])[f]
        : make_float4(0.f, 0.f, 0.f, 0.f);
    float* p = &sA[r * (K + 1) + f * 4];
    p[0] = v.x; p[1] = v.y; p[2] = v.z; p[3] = v.w;
  }
  __syncthreads();
  const int tc = tid & 15, tr = tid >> 4;
  const int c0 = tc * 4, r0 = tr * 4;
  float4 acc0 = {0,0,0,0}, acc1 = {0,0,0,0}, acc2 = {0,0,0,0}, acc3 = {0,0,0,0};
  const float* a0 = &sA[(r0 + 0) * (K + 1)];
  const float* a1 = &sA[(r0 + 1) * (K + 1)];
  const float* a2 = &sA[(r0 + 2) * (K + 1)];
  const float* a3 = &sA[(r0 + 3) * (K + 1)];
#pragma unroll 8
  for (int k = 0; k < K; ++k) {
    float4 w = *reinterpret_cast<const float4*>(&sW[k * 64 + c0]);
    float x0 = a0[k], x1 = a1[k], x2 = a2[k], x3 = a3[k];
    acc0.x = fmaf(x0, w.x, acc0.x); acc0.y = fmaf(x0, w.y, acc0.y);
    acc0.z = fmaf(x0, w.z, acc0.z); acc0.w = fmaf(x0, w.w, acc0.w);
    acc1.x = fmaf(x1, w.x, acc1.x); acc1.y = fmaf(x1, w.y, acc1.y);
    acc1.z = fmaf(x1, w.z, acc1.z); acc1.w = fmaf(x1, w.w, acc1.w);
    acc2.x = fmaf(x2, w.x, acc2.x); acc2.y = fmaf(x2, w.y, acc2.y);
    acc2.z = fmaf(x2, w.z, acc2.z); acc2.w = fmaf(x2, w.w, acc2.w);
    acc3.x = fmaf(x3, w.x, acc3.x); acc3.y = fmaf(x3, w.y, acc3.y);
    acc3.z = fmaf(x3, w.z, acc3.z); acc3.w = fmaf(x3, w.w, acc3.w);
  }
  float4 accs[4] = {acc0, acc1, acc2, acc3};
  const long gbase = (long)(c0 >> 3) * n * 8 + (c0 & 7);
#pragma unroll
  for (int i = 0; i < 4; ++i) {
    int row = row0 + r0 + i;
    if (row < n) {
      float s = SCALE ? dinv[row] : 1.0f;
      float4 o = make_float4(accs[i].x * s, accs[i].y * s,
                             accs[i].z * s, accs[i].w * s);
      *reinterpret_cast<float4*>(&C[gbase + (long)row * 8]) = o;
    }
  }
}

// ---------- channel-sliced GCN aggregate: sliced in [8][n][8], standard out ----------
// grid = 8 * ceil(n/32); group g = blockIdx&7 -> XCD g. 8 lanes/node.
template<bool RELU>
__global__ __launch_bounds__(256) void gcn_layer_kernel(
    const int* __restrict__ rowptr, const int* __restrict__ csr,
    const float* __restrict__ hs, const float* __restrict__ dinv,
    const float* __restrict__ bias, float* __restrict__ out, int n) {
  const int g = blockIdx.x & 7;
  const int node = (blockIdx.x >> 3) * 32 + (threadIdx.x >> 3);
  if (node >= n) return;
  const int ci = threadIdx.x & 7;
  const float* __restrict__ hsg = hs + (long)g * n * 8;  // contiguous 3.2MB slice
  const int beg = rowptr[node], end = rowptr[node + 1];
  float a0 = 0.f, a1 = 0.f, a2 = 0.f, a3 = 0.f;
  int j = beg;
  for (; j + 4 <= end; j += 4) {
    int s0 = csr[j], s1 = csr[j + 1], s2 = csr[j + 2], s3 = csr[j + 3];
    a0 += hsg[(long)s0 * 8 + ci];
    a1 += hsg[(long)s1 * 8 + ci];
    a2 += hsg[(long)s2 * 8 + ci];
    a3 += hsg[(long)s3 * 8 + ci];
  }
  for (; j < end; ++j) a0 += hsg[(long)csr[j] * 8 + ci];
  a0 += hsg[(long)node * 8 + ci];  // self-loop (hs pre-scaled by dinv)
  float acc = (a0 + a1) + (a2 + a3);
  const int c = g * 8 + ci;
  float v = fmaf(dinv[node], acc, bias[c]);
  if (RELU) v = fmaxf(v, 0.f);
  out[(long)node * 64 + c] = v;
}

// ---------- GAT logits from SLICED hg; outputs TRANSPOSED [head][node] ----------
__global__ void gat_alpha_kernel(
    const float* __restrict__ hg, const float* __restrict__ att_src, const float* __restrict__ att_dst,
    float* __restrict__ asT, float* __restrict__ adT, int n) {
  int i = blockIdx.x * 256 + threadIdx.x;
  if (i >= n * 8) return;
  int h = i / n, nrow = i - h * n;  // coalesced over nodes within head
  const float* hp = &hg[((long)h * n + nrow) * 8];
  float ss = 0.f, dd = 0.f;
#pragma unroll
  for (int c = 0; c < 8; ++c) {
    float v = hp[c];
    ss = fmaf(v, att_src[h * 8 + c], ss);
    dd = fmaf(v, att_dst[h * 8 + c], dd);
  }
  asT[(long)h * n + nrow] = ss;
  adT[(long)h * n + nrow] = dd;
}

// ---------- channel-sliced GAT: head h = blockIdx&7 == channel group ----------
__global__ __launch_bounds__(256) void gat_layer_kernel(
    const int* __restrict__ rowptr, const int* __restrict__ csr,
    const float* __restrict__ hg, const float* __restrict__ asT,
    const float* __restrict__ adT, const float* __restrict__ bg,
    float* __restrict__ out, int n) {
  const int h = blockIdx.x & 7;
  const int node = (blockIdx.x >> 3) * 32 + (threadIdx.x >> 3);
  if (node >= n) return;
  const int ci = threadIdx.x & 7;
  const float* __restrict__ hgh = hg + (long)h * n * 8;
  const float* __restrict__ as_h = asT + (long)h * n;
  const float adn = adT[(long)h * n + node];
  const int beg = rowptr[node], end = rowptr[node + 1];
  float z0 = 0.f, z1 = 0.f, z2 = 0.f, z3 = 0.f;
  float a0 = 0.f, a1 = 0.f, a2 = 0.f, a3 = 0.f;
  int j = beg;
  for (; j + 4 <= end; j += 4) {
    int s0 = csr[j], s1 = csr[j + 1], s2 = csr[j + 2], s3 = csr[j + 3];
    float p0 = __expf(leaky02(as_h[s0] + adn));
    float p1 = __expf(leaky02(as_h[s1] + adn));
    float p2 = __expf(leaky02(as_h[s2] + adn));
    float p3 = __expf(leaky02(as_h[s3] + adn));
    a0 = fmaf(p0, hgh[(long)s0 * 8 + ci], a0); z0 += p0;
    a1 = fmaf(p1, hgh[(long)s1 * 8 + ci], a1); z1 += p1;
    a2 = fmaf(p2, hgh[(long)s2 * 8 + ci], a2); z2 += p2;
    a3 = fmaf(p3, hgh[(long)s3 * 8 + ci], a3); z3 += p3;
  }
  for (; j < end; ++j) {
    int s = csr[j];
    float p = __expf(leaky02(as_h[s] + adn));
    a0 = fmaf(p, hgh[(long)s * 8 + ci], a0); z0 += p;
  }
  {  // self-loop
    float p = __expf(leaky02(as_h[node] + adn));
    a0 = fmaf(p, hgh[(long)node * 8 + ci], a0); z0 += p;
  }
  float z = (z0 + z1) + (z2 + z3);
  float acc = (a0 + a1) + (a2 + a3);
  const int c = h * 8 + ci;
  float v = fmaxf(fmaf(acc, 1.0f / z, bg[c]), 0.f);
  out[(long)node * 64 + c] = v;
}

extern "C" void kernel_launch(void* const* d_in, const int* in_sizes, int n_in,
                              void* d_out, int out_size, void* d_ws, size_t ws_size,
                              hipStream_t stream) {
  const float* x  = (const float*)d_in[0];
  const int* ei   = (const int*)d_in[1];
  const float* W0 = (const float*)d_in[2];
  const float* b0 = (const float*)d_in[3];
  const float* Wg = (const float*)d_in[4];
  const float* av = (const float*)d_in[5];
  const float* aw = (const float*)d_in[6];
  const float* bg = (const float*)d_in[7];
  const float* W2 = (const float*)d_in[8];
  const float* b2 = (const float*)d_in[9];
  const float* W3 = (const float*)d_in[10];
  const float* b3 = (const float*)d_in[11];

  const int N = in_sizes[0] / 128;
  const int E = in_sizes[1] / 2;
  const int* src = ei;
  const int* dst = ei + E;
  const int nbkt = (N + 255) >> 8;  // 391 for N=100000 (<=512 supported)

  char* base = (char*)d_ws;
  size_t off = 0;
  auto alloc = [&](size_t bytes) {
    void* p = base + off;
    off = (off + bytes + 255) & ~(size_t)255;
    return p;
  };
  int*   hist    = (int*)alloc((size_t)NB_PART * nbkt * 4);
  int*   bktBase = (int*)alloc((size_t)(nbkt + 1) * 4);
  int*   rowptr  = (int*)alloc((size_t)(N + 1) * 4);
  int*   csr     = (int*)alloc((size_t)E * 4);
  float* dinv    = (float*)alloc((size_t)N * 4);
  float* as_     = (float*)alloc((size_t)N * 8 * 4);
  float* ad_     = (float*)alloc((size_t)N * 8 * 4);
  float* bufA    = (float*)alloc((size_t)N * 64 * 4);
  float* bufB    = (float*)alloc((size_t)N * 64 * 4);
  int2*  part    = (int2*)bufA;  // 12.8MB alias; dead before first matmul writes bufA
  (void)ws_size; (void)n_in; (void)out_size;

  const int gN8   = (N * 8 + 255) / 256;
  const int gMM   = (N + 63) / 64;
  const int gAgg  = 8 * ((N + 31) / 32);  // channel-sliced aggregation grid

  // ---- CSR build: bucketed partition, L2-local scatter ----
  hist_kernel<<<NB_PART, 1024, 0, stream>>>(dst, hist, E, nbkt);
  pscan_kernel<<<1, 512, 0, stream>>>(hist, bktBase, nbkt, E);
  part_kernel<<<NB_PART, 1024, 0, stream>>>(src, dst, hist, bktBase, part, E, nbkt);
  build_kernel<<<nbkt, 256, 0, stream>>>(part, bktBase, rowptr, csr, dinv, N, E);

  // ---- GCN0 ----
  matmul_kernel<128, true><<<gMM, 256, 0, stream>>>(x, W0, dinv, bufA, N);
  gcn_layer_kernel<true><<<gAgg, 256, 0, stream>>>(rowptr, csr, bufA, dinv, b0, bufB, N);

  // ---- GAT ----
  matmul_kernel<64, false><<<gMM, 256, 0, stream>>>(bufB, Wg, nullptr, bufA, N);
  gat_alpha_kernel<<<gN8, 256, 0, stream>>>(bufA, av, aw, as_, ad_, N);
  gat_layer_kernel<<<gAgg, 256, 0, stream>>>(rowptr, csr, bufA, as_, ad_, bg, bufB, N);

  // ---- GCN2 ----
  matmul_kernel<64, true><<<gMM, 256, 0, stream>>>(bufB, W2, dinv, bufA, N);
  gcn_layer_kernel<true><<<gAgg, 256, 0, stream>>>(rowptr, csr, bufA, dinv, b2, bufB, N);

  // ---- GCN3: final layer, no relu, FLOAT32 out ----
  matmul_kernel<64, true><<<gMM, 256, 0, stream>>>(bufB, W3, dinv, bufA, N);
  gcn_layer_kernel<false><<<gAgg, 256, 0, stream>>>(rowptr, csr, bufA, dinv, b3,
                                                    (float*)d_out, N);
}